// Round 2
// baseline (315.983 us; speedup 1.0000x reference)
//
#include <hip/hip_runtime.h>
#include <float.h>
#include <math.h>

// VQ nearest-codebook: z_e (64,256,32,32) fp32 NCHW, codebook (512,256) fp32.
// token t = n*1024 + hw; feature d at z_e[n*262144 + d*1024 + hw].
// d_out: [0,65536) = q as float; [65536,...) = z_q fp32 NCHW.
//
// Ref model (proven): dists quantized by fp32 expansion with xsq~256;
// scan approximates m = x.w - 0.5|w|^2 (bf16-split MFMA, err ~2.5e-7),
// top-4 per token; if m-gap > MARGIN the argmax is final; else replicate the
// np fp32 quantized distance (xsq_np pairwise, fp64 dot -> fp32) tie->low k.
//
// This version SWAPS the MFMA operands (A = w codes as M-rows, B = x tokens as
// N-cols) so each lane accumulates scores of ONE token over 128 codes in
// registers -> the 512-wide argmax/top-4 is lane-local (in-register fold +
// one shfl_xor(32) pair merge + 8KB cross-wave merge). The former 256KB
// LDS score round-trip (and its 2.28M bank conflicts) is eliminated.

#define KCODES 512
#define DDIM   256
#define HWSZ   1024
#define TTOK   65536
#define TPB    128            // tokens per block
#define NBLK   (TTOK / TPB)   // 512
#define NCHUNK 16             // k-chunks of 16 dims
#define MARGIN 2.5e-4f

typedef short bf16x8 __attribute__((ext_vector_type(8)));   // 8 bf16 (4 VGPRs)
typedef float f32x16 __attribute__((ext_vector_type(16)));
typedef float f32x4  __attribute__((ext_vector_type(4)));

__device__ inline unsigned short bf16rne(float x) {
    union { float f; unsigned u; } a; a.f = x;
    unsigned r = a.u + (0x7fffu + ((a.u >> 16) & 1u));
    return (unsigned short)(r >> 16);
}
__device__ inline float bf16tof(unsigned short h) {
    union { unsigned u; float f; } b; b.u = ((unsigned)h) << 16; return b.f;
}

// sorted-descending top-4 insert, strict > (proven semantics from prior kernel)
__device__ __forceinline__ void top4_insert(float m, int c, float fb[4], int fi[4]) {
    if (m > fb[3]) {
        if (m > fb[1]) {
            if (m > fb[0]) {
                fb[3]=fb[2]; fi[3]=fi[2]; fb[2]=fb[1]; fi[2]=fi[1];
                fb[1]=fb[0]; fi[1]=fi[0]; fb[0]=m; fi[0]=c;
            } else {
                fb[3]=fb[2]; fi[3]=fi[2]; fb[2]=fb[1]; fi[2]=fi[1];
                fb[1]=m; fi[1]=c;
            }
        } else {
            if (m > fb[2]) { fb[3]=fb[2]; fi[3]=fi[2]; fb[2]=m; fi[2]=c; }
            else           { fb[3]=m; fi[3]=c; }
        }
    }
}

// ------------------------------------------------------------ wsq (np) -----
__global__ __launch_bounds__(256) void vq_wsq_np(const float* __restrict__ cb,
                                                 float* __restrict__ wsq) {
#pragma clang fp contract(off)
    const int k = blockIdx.x * 256 + threadIdx.x;
    if (k >= KCODES) return;
    const float* p = cb + (size_t)k * DDIM;
    float sh[2];
    #pragma unroll
    for (int h = 0; h < 2; ++h) {
        const float* q = p + h * 128;
        float r[8];
        #pragma unroll
        for (int j = 0; j < 8; ++j) { float v = q[j]; r[j] = v * v; }
        #pragma unroll
        for (int i = 8; i < 128; i += 8) {
            #pragma unroll
            for (int j = 0; j < 8; ++j) { float v = q[i + j]; float sq = v * v; r[j] = r[j] + sq; }
        }
        sh[h] = ((r[0] + r[1]) + (r[2] + r[3])) + ((r[4] + r[5]) + (r[6] + r[7]));
    }
    wsq[k] = sh[0] + sh[1];
}

// ------------------------------------------------------- w bf16 pack -------
// ws_w layout: [chunk c:16][part p:2][tile:16][lane:64][16B]  (512 KiB)
// element: code = tile*32 + (lane&31), d = c*16 + (lane>>5)*8 + j
__global__ __launch_bounds__(256) void vq_wpack(const float* __restrict__ cb,
                                                unsigned char* __restrict__ wsw) {
    const int gid = blockIdx.x * 256 + threadIdx.x;   // 16384 total
    const int k = gid >> 5, o = gid & 31;
    const int d0 = o * 8, c = o >> 1, half = o & 1;
    unsigned hi[4], lo[4];
    #pragma unroll
    for (int jj = 0; jj < 4; ++jj) {
        float v0 = cb[k * DDIM + d0 + 2 * jj];
        float v1 = cb[k * DDIM + d0 + 2 * jj + 1];
        unsigned short h0 = bf16rne(v0), h1 = bf16rne(v1);
        unsigned short l0 = bf16rne(v0 - bf16tof(h0));
        unsigned short l1 = bf16rne(v1 - bf16tof(h1));
        hi[jj] = (unsigned)h0 | ((unsigned)h1 << 16);
        lo[jj] = (unsigned)l0 | ((unsigned)l1 << 16);
    }
    const int tile = k >> 5, lane2 = (k & 31) + 32 * half;
    *(uint4*)(wsw + ((size_t)((c * 2 + 0) * 16 + tile) * 1024) + lane2 * 16) = make_uint4(hi[0], hi[1], hi[2], hi[3]);
    *(uint4*)(wsw + ((size_t)((c * 2 + 1) * 16 + tile) * 1024) + lane2 * 16) = make_uint4(lo[0], lo[1], lo[2], lo[3]);
}

// ---------------------------------------------------------------- main -----
// 512 blocks x 512 threads (8 waves). Block = 128 tokens x 512 codes.
// Wave wv: token tile mt = wv&3 (32 tokens), code half = wv>>2 (256 codes,
// streamed as 4 pairs of 32-code tiles). x staged in LDS in fragment order
// (same layout as before, now consumed as the B operand); w fragments (wsw,
// L2-resident) consumed directly as the A operand.
__global__ __launch_bounds__(512, 2) void vq_main(const float* __restrict__ z_e,
                                                  const float* __restrict__ cb,
                                                  const float* __restrict__ wsq,
                                                  const unsigned char* __restrict__ wsw,
                                                  float* __restrict__ out) {
    __shared__ __align__(16) unsigned char lds[131072 + 2048];

    const int tid = threadIdx.x;
    const int wv = tid >> 6, lane = tid & 63;
    const int tbase = blockIdx.x * TPB;
    const int n = tbase >> 10, hw0 = tbase & (HWSZ - 1);
    const float* zb = z_e + (size_t)n * (DDIM * HWSZ) + hw0;

    // ---- stage x -> LDS (bf16 hi/lo, fragment-packed, b128 writes) ----
    {
        const int tok = tid & 127, g = tid >> 7;
        const int mt = tok >> 5;
        const int lbase = (tok & 31) * 16;
        #pragma unroll
        for (int o = 0; o < 8; ++o) {
            const int d0 = g * 64 + o * 8;
            float v[8];
            #pragma unroll
            for (int j = 0; j < 8; ++j) v[j] = zb[(size_t)(d0 + j) * HWSZ + tok];
            unsigned hi[4], lo[4];
            #pragma unroll
            for (int jj = 0; jj < 4; ++jj) {
                unsigned short h0 = bf16rne(v[2 * jj]), h1 = bf16rne(v[2 * jj + 1]);
                unsigned short l0 = bf16rne(v[2 * jj] - bf16tof(h0));
                unsigned short l1 = bf16rne(v[2 * jj + 1] - bf16tof(h1));
                hi[jj] = (unsigned)h0 | ((unsigned)h1 << 16);
                lo[jj] = (unsigned)l0 | ((unsigned)l1 << 16);
            }
            const int c = d0 >> 4;
            const int off2 = lbase + 512 * ((d0 >> 3) & 1);
            *(uint4*)(lds + ((0 * 4 + mt) * 16 + c) * 1024 + off2) = make_uint4(hi[0], hi[1], hi[2], hi[3]);
            *(uint4*)(lds + ((1 * 4 + mt) * 16 + c) * 1024 + off2) = make_uint4(lo[0], lo[1], lo[2], lo[3]);
        }
    }
    // ---- stage 0.5*wsq -> LDS (2KB, broadcast-read in the fold) ----
    ((float*)(lds + 131072))[tid & 511] = 0.5f * wsq[tid & 511];

    __syncthreads();

    // ---- K-loop: stream 8 code tiles (4 pairs), fold top-4 in-register ----
    const int halfc = wv >> 2;          // code half: codes [halfc*256, +256)
    const int mt = wv & 3;              // token tile: tokens [mt*32, +32)
    const int hh = lane >> 5;           // which 16-row half of each 32-code tile
    const float* hwsqL = (const float*)(lds + 131072);

    #define LDW(c, p, t)   (*(const bf16x8*)(wsw + ((size_t)(((c) * 2 + (p)) * 16 + (t)) * 1024) + lane * 16))
    #define LDA(p, mm, c)  (*(const bf16x8*)(lds + (((p) * 4 + (mm)) * 16 + (c)) * 1024 + lane * 16))

    float fb[4] = {-FLT_MAX, -FLT_MAX, -FLT_MAX, -FLT_MAX};
    int   fi[4] = {KCODES, KCODES, KCODES, KCODES};

    for (int ctl = 0; ctl < 4; ++ctl) {
        const int ct0 = halfc * 8 + 2 * ctl;
        f32x16 a0, a1;
        #pragma unroll
        for (int r = 0; r < 16; ++r) { a0[r] = 0.f; a1[r] = 0.f; }
        #pragma unroll
        for (int c = 0; c < NCHUNK; ++c) {
            const bf16x8 Xh  = LDA(0, mt, c);
            const bf16x8 Xl  = LDA(1, mt, c);
            const bf16x8 W0h = LDW(c, 0, ct0);
            const bf16x8 W0l = LDW(c, 1, ct0);
            const bf16x8 W1h = LDW(c, 0, ct0 + 1);
            const bf16x8 W1l = LDW(c, 1, ct0 + 1);
            // m = xh*wh + xh*wl + xl*wh  (same 3 terms, A=w / B=x)
            a0 = __builtin_amdgcn_mfma_f32_32x32x16_bf16(W0h, Xh, a0, 0, 0, 0);
            a1 = __builtin_amdgcn_mfma_f32_32x32x16_bf16(W1h, Xh, a1, 0, 0, 0);
            a0 = __builtin_amdgcn_mfma_f32_32x32x16_bf16(W0l, Xh, a0, 0, 0, 0);
            a1 = __builtin_amdgcn_mfma_f32_32x32x16_bf16(W1l, Xh, a1, 0, 0, 0);
            a0 = __builtin_amdgcn_mfma_f32_32x32x16_bf16(W0h, Xl, a0, 0, 0, 0);
            a1 = __builtin_amdgcn_mfma_f32_32x32x16_bf16(W1h, Xl, a1, 0, 0, 0);
        }
        // C layout (32x32x16): col = lane&31 = token, row = (reg&3)+8*(reg>>2)+4*hh = code%32
        #pragma unroll
        for (int rq = 0; rq < 4; ++rq) {
            const f32x4 h40 = *(const f32x4*)(hwsqL + ct0 * 32 + rq * 8 + 4 * hh);
            const f32x4 h41 = *(const f32x4*)(hwsqL + (ct0 + 1) * 32 + rq * 8 + 4 * hh);
            #pragma unroll
            for (int rr = 0; rr < 4; ++rr) {
                top4_insert(a0[rq * 4 + rr] - h40[rr], ct0 * 32 + rr + 8 * rq + 4 * hh, fb, fi);
                top4_insert(a1[rq * 4 + rr] - h41[rr], (ct0 + 1) * 32 + rr + 8 * rq + 4 * hh, fb, fi);
            }
        }
    }

    // ---- pair merge: lane <-> lane^32 hold the two 16-row halves of the
    //      same token; merged -> top-4 of this wave's 256 codes ----
    {
        float sb[4]; int si[4];
        #pragma unroll
        for (int c = 0; c < 4; ++c) { sb[c] = __shfl_xor(fb[c], 32); si[c] = __shfl_xor(fi[c], 32); }
        #pragma unroll
        for (int c = 0; c < 4; ++c) top4_insert(sb[c], si[c], fb, fi);
    }

    // ---- publish per-wave top-4 (8KB), merge across code halves ----
    __syncthreads();                    // all LDS x reads done; reuse region
    float* candm = (float*)lds;                 // 1024 floats
    int*   candi = (int*)(lds + 4096);          // 1024 ints
    int*   bkArr = (int*)(lds + 8192);          // 128 ints
    if (lane < 32) {
        const int slot = ((mt * 2 + halfc) * 32 + lane) * 4;
        #pragma unroll
        for (int c = 0; c < 4; ++c) { candm[slot + c] = fb[c]; candi[slot + c] = fi[c]; }
    }
    __syncthreads();

    if (tid < TPB) {
        float g[4] = {-FLT_MAX, -FLT_MAX, -FLT_MAX, -FLT_MAX};
        int  gi[4] = {KCODES, KCODES, KCODES, KCODES};
        #pragma unroll
        for (int hf = 0; hf < 2; ++hf) {
            const int slot = (((tid >> 5) * 2 + hf) * 32 + (tid & 31)) * 4;
            #pragma unroll
            for (int c = 0; c < 4; ++c) top4_insert(candm[slot + c], candi[slot + c], g, gi);
        }

        int bestk;
        if (g[0] - g[1] > MARGIN) {
            bestk = gi[0];     // gap >> quantization window: no tie possible
        } else {
            const float* xa = zb + tid;
            // xsq: bitwise np pairwise fp32
            float xsq;
            {
#pragma clang fp contract(off)
                float sh[2];
                #pragma unroll
                for (int h = 0; h < 2; ++h) {
                    float rr[8];
                    #pragma unroll
                    for (int j = 0; j < 8; ++j) { float v = xa[(size_t)(h * 128 + j) * HWSZ]; rr[j] = v * v; }
                    #pragma unroll 2
                    for (int i = 8; i < 128; i += 8) {
                        #pragma unroll
                        for (int j = 0; j < 8; ++j) {
                            float v = xa[(size_t)(h * 128 + i + j) * HWSZ];
                            float sq = v * v;
                            rr[j] = rr[j] + sq;
                        }
                    }
                    sh[h] = ((rr[0] + rr[1]) + (rr[2] + rr[3])) + ((rr[4] + rr[5]) + (rr[6] + rr[7]));
                }
                xsq = sh[0] + sh[1];
            }
            float bestd = FLT_MAX; bestk = KCODES;
            for (int c = 0; c < 4; ++c) {
                if (c > 0 && g[0] - g[c] > MARGIN) break;
                const int idx = gi[c];
                const float* wr = cb + (size_t)idx * DDIM;
                double A = 0.0;
                #pragma unroll 4
                for (int d = 0; d < DDIM; ++d)
                    A = fma((double)xa[(size_t)d * HWSZ], (double)wr[d], A);
                {
#pragma clang fp contract(off)
                    const float xw = (float)A;
                    const float t1 = xsq - 2.0f * xw;
                    const float dist = t1 + wsq[idx];
                    if (dist < bestd || (dist == bestd && idx < bestk)) { bestd = dist; bestk = idx; }
                }
            }
        }
        out[tbase + tid] = (float)bestk;
        bkArr[tid] = bestk;
    }
    __syncthreads();

    // ---- z_q write (coalesced over tokens) ----
    {
        const int tk = tid & 127, s = tid >> 7;
        const int bk = bkArr[tk];
        const float* wr = cb + (size_t)bk * DDIM;
        float* zq = out + TTOK + (size_t)n * (DDIM * HWSZ) + hw0 + tk;
        #pragma unroll 4
        for (int i = 0; i < 64; ++i) {
            const int d = s * 64 + i;
            zq[(size_t)d * HWSZ] = wr[d];
        }
    }
}

// --------------------------------------------------------------- launch ----
extern "C" void kernel_launch(void* const* d_in, const int* in_sizes, int n_in,
                              void* d_out, int out_size, void* d_ws, size_t ws_size,
                              hipStream_t stream) {
    const float* z_e = (const float*)d_in[0];
    const float* cb  = (const float*)d_in[1];
    float* out = (float*)d_out;
    float* wsq = (float*)d_ws;                              // 2 KiB
    unsigned char* wsw = (unsigned char*)d_ws + 2048;       // 512 KiB fragment-packed w

    vq_wsq_np<<<2, 256, 0, stream>>>(cb, wsq);
    vq_wpack<<<64, 256, 0, stream>>>(cb, wsw);
    vq_main<<<NBLK, 512, 0, stream>>>(z_e, cb, wsq, wsw, out);
}

// Round 3
// 301.099 us; speedup vs baseline: 1.0494x; 1.0494x over previous
//
#include <hip/hip_runtime.h>
#include <float.h>
#include <math.h>

// VQ nearest-codebook: z_e (64,256,32,32) fp32 NCHW, codebook (512,256) fp32.
// token t = n*1024 + hw; feature d at z_e[n*262144 + d*1024 + hw].
// d_out: [0,65536) = q as float; [65536,...) = z_q fp32 NCHW.
//
// Ref model (proven): dists quantized by fp32 expansion with xsq~256;
// scan approximates m = x.w - 0.5|w|^2 (bf16-split MFMA, err ~2.5e-7),
// top-4 per token; if m-gap > MARGIN the argmax is final; else replicate the
// np fp32 quantized distance (xsq_np pairwise, fp64 dot -> fp32) tie->low k.
//
// Round-3 changes (latency-bound diagnosis: 90% no-issue at 2 waves/SIMD):
//  * TPB 128->64 tokens: x-LDS 128->64KB, total LDS 67KB -> 2 blocks/CU
//    -> 4 waves/SIMD and inter-block overlap of the adjudication phase.
//  * branchless top-4 insert (cmp+cndmask ladder, no divergent branches).
//  * z_q write: stage selected codebook rows into LDS with coalesced row
//    reads (1KB/wave-instr) instead of 64-way per-lane gathers from cb.

#define KCODES 512
#define DDIM   256
#define HWSZ   1024
#define TTOK   65536
#define TPB    64             // tokens per block
#define NBLK   (TTOK / TPB)   // 1024
#define NCHUNK 16             // k-chunks of 16 dims
#define MARGIN 2.5e-4f

// LDS map (bytes): [0, 66560) reuse region:
//   phase A: x fragments [p:2][mt:2][c:16][lane:64][16B] = 65536
//   phase B: candm (4KB) @0, candi (4KB) @4096
//   phase C: z_q row stage, 64 rows x 260 floats (1040B pitch) = 66560
// [66560, 68608): 0.5*wsq (512 floats)
// [68608, 68864): bkArr (64 ints)
#define HW_OFF 66560
#define BK_OFF 68608
#define LDS_SZ 68864
#define ZQ_PITCH 1040         // bytes per staged row (260 floats, 16B aligned)

typedef short bf16x8 __attribute__((ext_vector_type(8)));   // 8 bf16 (4 VGPRs)
typedef float f32x16 __attribute__((ext_vector_type(16)));
typedef float f32x4  __attribute__((ext_vector_type(4)));

__device__ inline unsigned short bf16rne(float x) {
    union { float f; unsigned u; } a; a.f = x;
    unsigned r = a.u + (0x7fffu + ((a.u >> 16) & 1u));
    return (unsigned short)(r >> 16);
}
__device__ inline float bf16tof(unsigned short h) {
    union { unsigned u; float f; } b; b.u = ((unsigned)h) << 16; return b.f;
}

// branchless sorted-descending top-4 insert, strict > (ties keep incumbent,
// exactly matching the proven branchy version's semantics)
__device__ __forceinline__ void top4_insert(float m, int c, float fb[4], int fi[4]) {
    #pragma unroll
    for (int l = 0; l < 4; ++l) {
        const bool s = m > fb[l];
        const float nm = s ? fb[l] : m;
        const int   nc = s ? fi[l] : c;
        fb[l] = s ? m : fb[l];
        fi[l] = s ? c : fi[l];
        m = nm; c = nc;
    }
}

// ------------------------------------------------------------ wsq (np) -----
__global__ __launch_bounds__(256) void vq_wsq_np(const float* __restrict__ cb,
                                                 float* __restrict__ wsq) {
#pragma clang fp contract(off)
    const int k = blockIdx.x * 256 + threadIdx.x;
    if (k >= KCODES) return;
    const float* p = cb + (size_t)k * DDIM;
    float sh[2];
    #pragma unroll
    for (int h = 0; h < 2; ++h) {
        const float* q = p + h * 128;
        float r[8];
        #pragma unroll
        for (int j = 0; j < 8; ++j) { float v = q[j]; r[j] = v * v; }
        #pragma unroll
        for (int i = 8; i < 128; i += 8) {
            #pragma unroll
            for (int j = 0; j < 8; ++j) { float v = q[i + j]; float sq = v * v; r[j] = r[j] + sq; }
        }
        sh[h] = ((r[0] + r[1]) + (r[2] + r[3])) + ((r[4] + r[5]) + (r[6] + r[7]));
    }
    wsq[k] = sh[0] + sh[1];
}

// ------------------------------------------------------- w bf16 pack -------
// ws_w layout: [chunk c:16][part p:2][tile:16][lane:64][16B]  (512 KiB)
// element: code = tile*32 + (lane&31), d = c*16 + (lane>>5)*8 + j
__global__ __launch_bounds__(256) void vq_wpack(const float* __restrict__ cb,
                                                unsigned char* __restrict__ wsw) {
    const int gid = blockIdx.x * 256 + threadIdx.x;   // 16384 total
    const int k = gid >> 5, o = gid & 31;
    const int d0 = o * 8, c = o >> 1, half = o & 1;
    unsigned hi[4], lo[4];
    #pragma unroll
    for (int jj = 0; jj < 4; ++jj) {
        float v0 = cb[k * DDIM + d0 + 2 * jj];
        float v1 = cb[k * DDIM + d0 + 2 * jj + 1];
        unsigned short h0 = bf16rne(v0), h1 = bf16rne(v1);
        unsigned short l0 = bf16rne(v0 - bf16tof(h0));
        unsigned short l1 = bf16rne(v1 - bf16tof(h1));
        hi[jj] = (unsigned)h0 | ((unsigned)h1 << 16);
        lo[jj] = (unsigned)l0 | ((unsigned)l1 << 16);
    }
    const int tile = k >> 5, lane2 = (k & 31) + 32 * half;
    *(uint4*)(wsw + ((size_t)((c * 2 + 0) * 16 + tile) * 1024) + lane2 * 16) = make_uint4(hi[0], hi[1], hi[2], hi[3]);
    *(uint4*)(wsw + ((size_t)((c * 2 + 1) * 16 + tile) * 1024) + lane2 * 16) = make_uint4(lo[0], lo[1], lo[2], lo[3]);
}

// ---------------------------------------------------------------- main -----
// 1024 blocks x 512 threads (8 waves). Block = 64 tokens x 512 codes.
// Wave wv: token tile mt = wv&1 (32 tokens), code quarter qc = wv>>1
// (128 codes as 2 pairs of 32-code tiles). x staged in LDS fragment order
// (B operand); w fragments (wsw, L2-resident) read directly as A operand.
__global__ __launch_bounds__(512, 4) void vq_main(const float* __restrict__ z_e,
                                                  const float* __restrict__ cb,
                                                  const float* __restrict__ wsq,
                                                  const unsigned char* __restrict__ wsw,
                                                  float* __restrict__ out) {
    __shared__ __align__(16) unsigned char lds[LDS_SZ];

    const int tid = threadIdx.x;
    const int wv = tid >> 6, lane = tid & 63;
    const int tbase = blockIdx.x * TPB;
    const int n = tbase >> 10, hw0 = tbase & (HWSZ - 1);
    const float* zb = z_e + (size_t)n * (DDIM * HWSZ) + hw0;

    // ---- stage x -> LDS (bf16 hi/lo, fragment-packed, b128 writes) ----
    {
        const int tok = tid & 63, g = tid >> 6;     // 8 threads per token
        const int mtS = tok >> 5;
        const int lbase = (tok & 31) * 16;
        #pragma unroll
        for (int o = 0; o < 4; ++o) {
            const int d0 = g * 32 + o * 8;
            float v[8];
            #pragma unroll
            for (int j = 0; j < 8; ++j) v[j] = zb[(size_t)(d0 + j) * HWSZ + tok];
            unsigned hi[4], lo[4];
            #pragma unroll
            for (int jj = 0; jj < 4; ++jj) {
                unsigned short h0 = bf16rne(v[2 * jj]), h1 = bf16rne(v[2 * jj + 1]);
                unsigned short l0 = bf16rne(v[2 * jj] - bf16tof(h0));
                unsigned short l1 = bf16rne(v[2 * jj + 1] - bf16tof(h1));
                hi[jj] = (unsigned)h0 | ((unsigned)h1 << 16);
                lo[jj] = (unsigned)l0 | ((unsigned)l1 << 16);
            }
            const int c = d0 >> 4;
            const int off2 = lbase + 512 * ((d0 >> 3) & 1);
            *(uint4*)(lds + ((0 * 2 + mtS) * 16 + c) * 1024 + off2) = make_uint4(hi[0], hi[1], hi[2], hi[3]);
            *(uint4*)(lds + ((1 * 2 + mtS) * 16 + c) * 1024 + off2) = make_uint4(lo[0], lo[1], lo[2], lo[3]);
        }
    }
    // ---- stage 0.5*wsq -> LDS (2KB, broadcast-read in the fold) ----
    ((float*)(lds + HW_OFF))[tid] = 0.5f * wsq[tid];

    __syncthreads();

    // ---- K-loop: 2 pairs of 32-code tiles, fold top-4 in-register ----
    const int qc = wv >> 1;             // code quarter: codes [qc*128, +128)
    const int mt = wv & 1;              // token tile: tokens [mt*32, +32)
    const int hh = lane >> 5;           // which 16-row half of each 32-code tile
    const float* hwsqL = (const float*)(lds + HW_OFF);

    #define LDW(c, p, t)   (*(const bf16x8*)(wsw + ((size_t)(((c) * 2 + (p)) * 16 + (t)) * 1024) + lane * 16))
    #define LDA(p, mm, c)  (*(const bf16x8*)(lds + (((p) * 2 + (mm)) * 16 + (c)) * 1024 + lane * 16))

    float fb[4] = {-FLT_MAX, -FLT_MAX, -FLT_MAX, -FLT_MAX};
    int   fi[4] = {KCODES, KCODES, KCODES, KCODES};

    #pragma unroll
    for (int pr = 0; pr < 2; ++pr) {
        const int ct0 = qc * 4 + 2 * pr;
        f32x16 a0, a1;
        #pragma unroll
        for (int r = 0; r < 16; ++r) { a0[r] = 0.f; a1[r] = 0.f; }
        #pragma unroll
        for (int c = 0; c < NCHUNK; ++c) {
            const bf16x8 Xh  = LDA(0, mt, c);
            const bf16x8 Xl  = LDA(1, mt, c);
            const bf16x8 W0h = LDW(c, 0, ct0);
            const bf16x8 W0l = LDW(c, 1, ct0);
            const bf16x8 W1h = LDW(c, 0, ct0 + 1);
            const bf16x8 W1l = LDW(c, 1, ct0 + 1);
            // m = xh*wh + xh*wl + xl*wh  (A=w / B=x)
            a0 = __builtin_amdgcn_mfma_f32_32x32x16_bf16(W0h, Xh, a0, 0, 0, 0);
            a1 = __builtin_amdgcn_mfma_f32_32x32x16_bf16(W1h, Xh, a1, 0, 0, 0);
            a0 = __builtin_amdgcn_mfma_f32_32x32x16_bf16(W0l, Xh, a0, 0, 0, 0);
            a1 = __builtin_amdgcn_mfma_f32_32x32x16_bf16(W1l, Xh, a1, 0, 0, 0);
            a0 = __builtin_amdgcn_mfma_f32_32x32x16_bf16(W0h, Xl, a0, 0, 0, 0);
            a1 = __builtin_amdgcn_mfma_f32_32x32x16_bf16(W1h, Xl, a1, 0, 0, 0);
        }
        // C layout (32x32x16): col = lane&31 = token, row = (reg&3)+8*(reg>>2)+4*hh = code%32
        #pragma unroll
        for (int rq = 0; rq < 4; ++rq) {
            const f32x4 h40 = *(const f32x4*)(hwsqL + ct0 * 32 + rq * 8 + 4 * hh);
            const f32x4 h41 = *(const f32x4*)(hwsqL + (ct0 + 1) * 32 + rq * 8 + 4 * hh);
            #pragma unroll
            for (int rr = 0; rr < 4; ++rr) {
                top4_insert(a0[rq * 4 + rr] - h40[rr], ct0 * 32 + rr + 8 * rq + 4 * hh, fb, fi);
                top4_insert(a1[rq * 4 + rr] - h41[rr], (ct0 + 1) * 32 + rr + 8 * rq + 4 * hh, fb, fi);
            }
        }
    }

    // ---- pair merge: lane <-> lane^32 hold the two 16-row halves of the
    //      same token; merged -> top-4 of this wave's 128 codes ----
    {
        float sb[4]; int si[4];
        #pragma unroll
        for (int c = 0; c < 4; ++c) { sb[c] = __shfl_xor(fb[c], 32); si[c] = __shfl_xor(fi[c], 32); }
        #pragma unroll
        for (int c = 0; c < 4; ++c) top4_insert(sb[c], si[c], fb, fi);
    }

    // ---- publish per-wave top-4 (8KB), merge across code quarters ----
    __syncthreads();                    // all LDS x reads done; reuse region
    float* candm = (float*)lds;                 // 1024 floats
    int*   candi = (int*)(lds + 4096);          // 1024 ints
    int*   bkArr = (int*)(lds + BK_OFF);        // 64 ints
    if (lane < 32) {
        const int slot = (qc * 64 + mt * 32 + lane) * 4;
        #pragma unroll
        for (int c = 0; c < 4; ++c) { candm[slot + c] = fb[c]; candi[slot + c] = fi[c]; }
    }
    __syncthreads();

    if (tid < TPB) {
        float g[4] = {-FLT_MAX, -FLT_MAX, -FLT_MAX, -FLT_MAX};
        int  gi[4] = {KCODES, KCODES, KCODES, KCODES};
        #pragma unroll
        for (int q4 = 0; q4 < 4; ++q4) {
            const int slot = (q4 * 64 + tid) * 4;
            #pragma unroll
            for (int c = 0; c < 4; ++c) top4_insert(candm[slot + c], candi[slot + c], g, gi);
        }

        int bestk;
        if (g[0] - g[1] > MARGIN) {
            bestk = gi[0];     // gap >> quantization window: no tie possible
        } else {
            const float* xa = zb + tid;
            // xsq: bitwise np pairwise fp32
            float xsq;
            {
#pragma clang fp contract(off)
                float sh[2];
                #pragma unroll
                for (int h = 0; h < 2; ++h) {
                    float rr[8];
                    #pragma unroll
                    for (int j = 0; j < 8; ++j) { float v = xa[(size_t)(h * 128 + j) * HWSZ]; rr[j] = v * v; }
                    #pragma unroll 2
                    for (int i = 8; i < 128; i += 8) {
                        #pragma unroll
                        for (int j = 0; j < 8; ++j) {
                            float v = xa[(size_t)(h * 128 + i + j) * HWSZ];
                            float sq = v * v;
                            rr[j] = rr[j] + sq;
                        }
                    }
                    sh[h] = ((rr[0] + rr[1]) + (rr[2] + rr[3])) + ((rr[4] + rr[5]) + (rr[6] + rr[7]));
                }
                xsq = sh[0] + sh[1];
            }
            float bestd = FLT_MAX; bestk = KCODES;
            for (int c = 0; c < 4; ++c) {
                if (c > 0 && g[0] - g[c] > MARGIN) break;
                const int idx = gi[c];
                const float* wr = cb + (size_t)idx * DDIM;
                double A = 0.0;
                #pragma unroll 4
                for (int d = 0; d < DDIM; ++d)
                    A = fma((double)xa[(size_t)d * HWSZ], (double)wr[d], A);
                {
#pragma clang fp contract(off)
                    const float xw = (float)A;
                    const float t1 = xsq - 2.0f * xw;
                    const float dist = t1 + wsq[idx];
                    if (dist < bestd || (dist == bestd && idx < bestk)) { bestd = dist; bestk = idx; }
                }
            }
        }
        out[tbase + tid] = (float)bestk;
        bkArr[tid] = bestk;
    }
    __syncthreads();

    // ---- z_q: stage selected rows into LDS (coalesced row reads) ----
    {
        #pragma unroll
        for (int rr = 0; rr < 8; ++rr) {
            const int r = wv * 8 + rr;
            const int bk = ((const int*)(lds + BK_OFF))[r];       // wave-uniform
            const float4 vv = *(const float4*)(cb + (size_t)bk * DDIM + lane * 4);
            *(float4*)(lds + r * ZQ_PITCH + lane * 16) = vv;
        }
    }
    __syncthreads();

    // ---- z_q write (coalesced over tokens, sourced from LDS) ----
    {
        const int tk = tid & 63, s = tid >> 6;
        float* zq = out + TTOK + (size_t)n * (DDIM * HWSZ) + hw0 + tk;
        #pragma unroll
        for (int i = 0; i < 32; i += 4) {
            const f32x4 v = *(const f32x4*)(lds + tk * ZQ_PITCH + (s * 32 + i) * 4);
            #pragma unroll
            for (int j = 0; j < 4; ++j)
                zq[(size_t)(s * 32 + i + j) * HWSZ] = v[j];
        }
    }
}

// --------------------------------------------------------------- launch ----
extern "C" void kernel_launch(void* const* d_in, const int* in_sizes, int n_in,
                              void* d_out, int out_size, void* d_ws, size_t ws_size,
                              hipStream_t stream) {
    const float* z_e = (const float*)d_in[0];
    const float* cb  = (const float*)d_in[1];
    float* out = (float*)d_out;
    float* wsq = (float*)d_ws;                              // 2 KiB
    unsigned char* wsw = (unsigned char*)d_ws + 2048;       // 512 KiB fragment-packed w

    vq_wsq_np<<<2, 256, 0, stream>>>(cb, wsq);
    vq_wpack<<<64, 256, 0, stream>>>(cb, wsw);
    vq_main<<<NBLK, 512, 0, stream>>>(z_e, cb, wsq, wsw, out);
}

// Round 5
// 184.202 us; speedup vs baseline: 1.7154x; 1.6346x over previous
//
#include <hip/hip_runtime.h>
#include <float.h>
#include <math.h>

// VQ nearest-codebook: z_e (64,256,32,32) fp32 NCHW, codebook (512,256) fp32.
// token t = n*1024 + hw; feature d at z_e[n*262144 + d*1024 + hw].
// d_out: [0,65536) = q as float; [65536,...) = z_q fp32 NCHW.
//
// Ref model (proven): dists quantized by fp32 expansion with xsq~256;
// scan approximates m = x.w - 0.5|w|^2 (bf16-split MFMA, err ~2.5e-7),
// top-4 per token; if m-gap > MARGIN the argmax is final; else replicate the
// np fp32 quantized distance (xsq_np pairwise, fp64 dot -> fp32) tie->low k.
//
// Round-4 changes (diagnosis: adjudication = TPB-invariant single-wave serial
// tail ~ dominating per-block wall time; fires in ~96% of blocks):
//  * worklist adjudication: needy tokens pushed to LDS, processed by ALL 8
//    waves, one WAVE per item: xsq via 16-lane exact-order stripe fold +
//    shfl butterfly (bitwise np pairwise), fp64 dots lane-parallel (4 fma +
//    fp64 butterfly; order-free at fp32 granularity), fp32 finish bitwise.
//  * K-loop: explicit double-buffered W/X register prefetch (VGPR cap 128).
//  * vq_wsq_np: 32 blocks, 16 lanes/code, same exact-order scheme.

#define KCODES 512
#define DDIM   256
#define HWSZ   1024
#define TTOK   65536
#define TPB    64             // tokens per block
#define NBLK   (TTOK / TPB)   // 1024
#define NCHUNK 16             // k-chunks of 16 dims
#define MARGIN 2.5e-4f

// LDS map (bytes): [0, 66560) reuse region:
//   phase A: x fragments [p:2][mt:2][c:16][lane:64][16B] = 65536
//   phase B: candm (4KB) @0, candi (4KB) @4096, worklist @8192..10512
//   phase C: z_q row stage, 64 rows x 260 floats (1040B pitch) = 66560
// [66560, 68608): 0.5*wsq (512 floats)
// [68608, 68864): bkArr (64 ints)
#define HW_OFF 66560
#define BK_OFF 68608
#define LDS_SZ 68864
#define ZQ_PITCH 1040         // bytes per staged row (260 floats, 16B aligned)

typedef short bf16x8 __attribute__((ext_vector_type(8)));   // 8 bf16 (4 VGPRs)
typedef float f32x16 __attribute__((ext_vector_type(16)));
typedef float f32x4  __attribute__((ext_vector_type(4)));

__device__ inline unsigned short bf16rne(float x) {
    union { float f; unsigned u; } a; a.f = x;
    unsigned r = a.u + (0x7fffu + ((a.u >> 16) & 1u));
    return (unsigned short)(r >> 16);
}
__device__ inline float bf16tof(unsigned short h) {
    union { unsigned u; float f; } b; b.u = ((unsigned)h) << 16; return b.f;
}

// branchless sorted-descending top-4 insert, strict > (ties keep incumbent)
__device__ __forceinline__ void top4_insert(float m, int c, float fb[4], int fi[4]) {
    #pragma unroll
    for (int l = 0; l < 4; ++l) {
        const bool s = m > fb[l];
        const float nm = s ? fb[l] : m;
        const int   nc = s ? fi[l] : c;
        fb[l] = s ? m : fb[l];
        fi[l] = s ? c : fi[l];
        m = nm; c = nc;
    }
}

// ------------------------------------------------------------ wsq (np) -----
// 16 lanes per code; lane s = h*8+j runs stripe j of half h in exact np order
// (16-term serial fold), then shfl butterfly reproduces
// ((r0+r1)+(r2+r3))+((r4+r5)+(r6+r7)) and sh0+sh1 bitwise.
__global__ __launch_bounds__(256) void vq_wsq_np(const float* __restrict__ cb,
                                                 float* __restrict__ wsq) {
    const int tid = threadIdx.x;
    const int k = blockIdx.x * 16 + (tid >> 4);
    const int s = tid & 15, h2 = s >> 3, j2 = s & 7;
    const float* p = cb + (size_t)k * DDIM + h2 * 128 + j2;
    float v[16];
    #pragma unroll
    for (int i = 0; i < 16; ++i) v[i] = p[i * 8];
    float rr;
    {
#pragma clang fp contract(off)
        rr = v[0] * v[0];
        #pragma unroll
        for (int i = 1; i < 16; ++i) { float sq = v[i] * v[i]; rr = rr + sq; }
    }
    float t = rr;
    t = t + __shfl_xor(t, 1);
    t = t + __shfl_xor(t, 2);
    t = t + __shfl_xor(t, 4);
    t = t + __shfl_xor(t, 8);
    if (s == 0) wsq[k] = t;
}

// ------------------------------------------------------- w bf16 pack -------
// ws_w layout: [chunk c:16][part p:2][tile:16][lane:64][16B]  (512 KiB)
// element: code = tile*32 + (lane&31), d = c*16 + (lane>>5)*8 + j
__global__ __launch_bounds__(256) void vq_wpack(const float* __restrict__ cb,
                                                unsigned char* __restrict__ wsw) {
    const int gid = blockIdx.x * 256 + threadIdx.x;   // 16384 total
    const int k = gid >> 5, o = gid & 31;
    const int d0 = o * 8, c = o >> 1, half = o & 1;
    unsigned hi[4], lo[4];
    #pragma unroll
    for (int jj = 0; jj < 4; ++jj) {
        float v0 = cb[k * DDIM + d0 + 2 * jj];
        float v1 = cb[k * DDIM + d0 + 2 * jj + 1];
        unsigned short h0 = bf16rne(v0), h1 = bf16rne(v1);
        unsigned short l0 = bf16rne(v0 - bf16tof(h0));
        unsigned short l1 = bf16rne(v1 - bf16tof(h1));
        hi[jj] = (unsigned)h0 | ((unsigned)h1 << 16);
        lo[jj] = (unsigned)l0 | ((unsigned)l1 << 16);
    }
    const int tile = k >> 5, lane2 = (k & 31) + 32 * half;
    *(uint4*)(wsw + ((size_t)((c * 2 + 0) * 16 + tile) * 1024) + lane2 * 16) = make_uint4(hi[0], hi[1], hi[2], hi[3]);
    *(uint4*)(wsw + ((size_t)((c * 2 + 1) * 16 + tile) * 1024) + lane2 * 16) = make_uint4(lo[0], lo[1], lo[2], lo[3]);
}

// ---------------------------------------------------------------- main -----
// 1024 blocks x 512 threads (8 waves). Block = 64 tokens x 512 codes.
// Wave wv: token tile mt = wv&1 (32 tokens), code quarter qc = wv>>1.
__global__ __launch_bounds__(512, 4) void vq_main(const float* __restrict__ z_e,
                                                  const float* __restrict__ cb,
                                                  const float* __restrict__ wsq,
                                                  const unsigned char* __restrict__ wsw,
                                                  float* __restrict__ out) {
    __shared__ __align__(16) unsigned char lds[LDS_SZ];

    const int tid = threadIdx.x;
    const int wv = tid >> 6, lane = tid & 63;
    const int tbase = blockIdx.x * TPB;
    const int n = tbase >> 10, hw0 = tbase & (HWSZ - 1);
    const float* zb = z_e + (size_t)n * (DDIM * HWSZ) + hw0;

    // ---- stage x -> LDS (bf16 hi/lo, fragment-packed, b128 writes) ----
    {
        const int tok = tid & 63, g = tid >> 6;     // 8 threads per token
        const int mtS = tok >> 5;
        const int lbase = (tok & 31) * 16;
        #pragma unroll
        for (int o = 0; o < 4; ++o) {
            const int d0 = g * 32 + o * 8;
            float v[8];
            #pragma unroll
            for (int j = 0; j < 8; ++j) v[j] = zb[(size_t)(d0 + j) * HWSZ + tok];
            unsigned hi[4], lo[4];
            #pragma unroll
            for (int jj = 0; jj < 4; ++jj) {
                unsigned short h0 = bf16rne(v[2 * jj]), h1 = bf16rne(v[2 * jj + 1]);
                unsigned short l0 = bf16rne(v[2 * jj] - bf16tof(h0));
                unsigned short l1 = bf16rne(v[2 * jj + 1] - bf16tof(h1));
                hi[jj] = (unsigned)h0 | ((unsigned)h1 << 16);
                lo[jj] = (unsigned)l0 | ((unsigned)l1 << 16);
            }
            const int c = d0 >> 4;
            const int off2 = lbase + 512 * ((d0 >> 3) & 1);
            *(uint4*)(lds + ((0 * 2 + mtS) * 16 + c) * 1024 + off2) = make_uint4(hi[0], hi[1], hi[2], hi[3]);
            *(uint4*)(lds + ((1 * 2 + mtS) * 16 + c) * 1024 + off2) = make_uint4(lo[0], lo[1], lo[2], lo[3]);
        }
    }
    // ---- stage 0.5*wsq -> LDS (2KB, broadcast-read in the fold) ----
    ((float*)(lds + HW_OFF))[tid] = 0.5f * wsq[tid];

    __syncthreads();

    // ---- K-loop: 2 pairs of 32-code tiles, reg-double-buffered, fold ----
    const int qc = wv >> 1;             // code quarter: codes [qc*128, +128)
    const int mt = wv & 1;              // token tile: tokens [mt*32, +32)
    const int hh = lane >> 5;           // which 16-row half of each 32-code tile
    const float* hwsqL = (const float*)(lds + HW_OFF);

    #define LDW(c, p, t)   (*(const bf16x8*)(wsw + ((size_t)(((c) * 2 + (p)) * 16 + (t)) * 1024) + lane * 16))
    #define LDA(p, mm, c)  (*(const bf16x8*)(lds + (((p) * 2 + (mm)) * 16 + (c)) * 1024 + lane * 16))

    float fb[4] = {-FLT_MAX, -FLT_MAX, -FLT_MAX, -FLT_MAX};
    int   fi[4] = {KCODES, KCODES, KCODES, KCODES};

    #pragma unroll
    for (int pr = 0; pr < 2; ++pr) {
        const int ct0 = qc * 4 + 2 * pr;
        f32x16 a0, a1;
        #pragma unroll
        for (int r = 0; r < 16; ++r) { a0[r] = 0.f; a1[r] = 0.f; }
        bf16x8 Xc[2][2], Wc[2][4];
        Xc[0][0] = LDA(0, mt, 0);  Xc[0][1] = LDA(1, mt, 0);
        Wc[0][0] = LDW(0, 0, ct0); Wc[0][1] = LDW(0, 1, ct0);
        Wc[0][2] = LDW(0, 0, ct0 + 1); Wc[0][3] = LDW(0, 1, ct0 + 1);
        #pragma unroll
        for (int c = 0; c < NCHUNK; ++c) {
            const int cur = c & 1, nxt = cur ^ 1;
            if (c + 1 < NCHUNK) {
                Xc[nxt][0] = LDA(0, mt, c + 1);  Xc[nxt][1] = LDA(1, mt, c + 1);
                Wc[nxt][0] = LDW(c + 1, 0, ct0); Wc[nxt][1] = LDW(c + 1, 1, ct0);
                Wc[nxt][2] = LDW(c + 1, 0, ct0 + 1); Wc[nxt][3] = LDW(c + 1, 1, ct0 + 1);
            }
            // m = xh*wh + xh*wl + xl*wh  (A=w / B=x)
            a0 = __builtin_amdgcn_mfma_f32_32x32x16_bf16(Wc[cur][0], Xc[cur][0], a0, 0, 0, 0);
            a1 = __builtin_amdgcn_mfma_f32_32x32x16_bf16(Wc[cur][2], Xc[cur][0], a1, 0, 0, 0);
            a0 = __builtin_amdgcn_mfma_f32_32x32x16_bf16(Wc[cur][1], Xc[cur][0], a0, 0, 0, 0);
            a1 = __builtin_amdgcn_mfma_f32_32x32x16_bf16(Wc[cur][3], Xc[cur][0], a1, 0, 0, 0);
            a0 = __builtin_amdgcn_mfma_f32_32x32x16_bf16(Wc[cur][0], Xc[cur][1], a0, 0, 0, 0);
            a1 = __builtin_amdgcn_mfma_f32_32x32x16_bf16(Wc[cur][2], Xc[cur][1], a1, 0, 0, 0);
        }
        // C layout (32x32x16): col = lane&31 = token, row = (reg&3)+8*(reg>>2)+4*hh = code%32
        #pragma unroll
        for (int rq = 0; rq < 4; ++rq) {
            const f32x4 h40 = *(const f32x4*)(hwsqL + ct0 * 32 + rq * 8 + 4 * hh);
            const f32x4 h41 = *(const f32x4*)(hwsqL + (ct0 + 1) * 32 + rq * 8 + 4 * hh);
            #pragma unroll
            for (int rr = 0; rr < 4; ++rr) {
                top4_insert(a0[rq * 4 + rr] - h40[rr], ct0 * 32 + rr + 8 * rq + 4 * hh, fb, fi);
                top4_insert(a1[rq * 4 + rr] - h41[rr], (ct0 + 1) * 32 + rr + 8 * rq + 4 * hh, fb, fi);
            }
        }
    }

    // ---- pair merge: lane <-> lane^32 (two 16-row halves of same token) ----
    {
        float sb[4]; int si[4];
        #pragma unroll
        for (int c = 0; c < 4; ++c) { sb[c] = __shfl_xor(fb[c], 32); si[c] = __shfl_xor(fi[c], 32); }
        #pragma unroll
        for (int c = 0; c < 4; ++c) top4_insert(sb[c], si[c], fb, fi);
    }

    // ---- publish per-wave top-4, merge across code quarters ----
    __syncthreads();                    // all LDS x reads done; reuse region
    float* candm = (float*)lds;                 // 1024 floats
    int*   candi = (int*)(lds + 4096);          // 1024 ints
    int*   wlCnt = (int*)(lds + 8192);
    int*   wlTok = (int*)(lds + 8208);          // 64 ints
    int*   wlGi  = (int*)(lds + 8464);          // 64*4 ints
    float* wlG   = (float*)(lds + 9488);        // 64*4 floats
    int*   bkArr = (int*)(lds + BK_OFF);        // 64 ints
    if (lane < 32) {
        const int slot = (qc * 64 + mt * 32 + lane) * 4;
        #pragma unroll
        for (int c = 0; c < 4; ++c) { candm[slot + c] = fb[c]; candi[slot + c] = fi[c]; }
    }
    if (tid == 0) *wlCnt = 0;
    __syncthreads();

    if (tid < TPB) {
        float g[4] = {-FLT_MAX, -FLT_MAX, -FLT_MAX, -FLT_MAX};
        int  gi[4] = {KCODES, KCODES, KCODES, KCODES};
        #pragma unroll
        for (int q4 = 0; q4 < 4; ++q4) {
            const int slot = (q4 * 64 + tid) * 4;
            #pragma unroll
            for (int c = 0; c < 4; ++c) top4_insert(candm[slot + c], candi[slot + c], g, gi);
        }
        if (g[0] - g[1] > MARGIN) {
            // gap >> quantization window: argmax final, no tie possible
            out[tbase + tid] = (float)gi[0];
            bkArr[tid] = gi[0];
        } else {
            const int slot = atomicAdd(wlCnt, 1);
            wlTok[slot] = tid;
            #pragma unroll
            for (int c = 0; c < 4; ++c) { wlGi[slot * 4 + c] = gi[c]; wlG[slot * 4 + c] = g[c]; }
        }
    }
    __syncthreads();

    // ---- adjudication: all 8 waves round-robin the worklist; one wave/item ----
    {
        const int nIt = *wlCnt;
        for (int it = wv; it < nIt; it += 8) {
            const int tok = wlTok[it];
            const float g0 = wlG[it * 4];
            const float* xa = zb + tok;

            // xsq: bitwise np pairwise. Lane s<16 (s = h*8+j) runs stripe j of
            // half h as a serial 16-term fold; butterfly reproduces the exact
            // pairwise combine ((r0+r1)+(r2+r3))+((r4+r5)+(r6+r7)), sh0+sh1.
            float xsq;
            {
                const int h2 = (lane >> 3) & 1, j2 = lane & 7;
                float v[16];
                if (lane < 16) {
                    #pragma unroll
                    for (int i = 0; i < 16; ++i)
                        v[i] = xa[(size_t)(h2 * 128 + i * 8 + j2) * HWSZ];
                } else {
                    #pragma unroll
                    for (int i = 0; i < 16; ++i) v[i] = 0.f;
                }
                float rr;
                {
#pragma clang fp contract(off)
                    rr = v[0] * v[0];
                    #pragma unroll
                    for (int i = 1; i < 16; ++i) { float sq = v[i] * v[i]; rr = rr + sq; }
                }
                float t = rr;
                t = t + __shfl_xor(t, 1);
                t = t + __shfl_xor(t, 2);
                t = t + __shfl_xor(t, 4);
                t = t + __shfl_xor(t, 8);
                xsq = __shfl(t, 0);
            }

            // x column into regs for the dots (lane d0 = lane, +64 strides)
            double xv[4];
            #pragma unroll
            for (int i = 0; i < 4; ++i)
                xv[i] = (double)xa[(size_t)(lane + 64 * i) * HWSZ];

            float bestd = FLT_MAX; int bestk = KCODES;
            #pragma unroll
            for (int c = 0; c < 4; ++c) {
                const float gc = wlG[it * 4 + c];
                if (c > 0 && g0 - gc > MARGIN) break;   // wave-uniform
                const int idx = wlGi[it * 4 + c];
                const float* wr = cb + (size_t)idx * DDIM;
                double A = 0.0;
                #pragma unroll
                for (int i = 0; i < 4; ++i)
                    A = fma((double)wr[lane + 64 * i], xv[i], A);
                // fp64 butterfly reduce (order-free: 29 spare bits vs fp32)
                A = A + __shfl_xor(A, 1);
                A = A + __shfl_xor(A, 2);
                A = A + __shfl_xor(A, 4);
                A = A + __shfl_xor(A, 8);
                A = A + __shfl_xor(A, 16);
                A = A + __shfl_xor(A, 32);
                float dist;
                {
#pragma clang fp contract(off)
                    const float xw = (float)A;
                    const float t1 = xsq - 2.0f * xw;
                    dist = t1 + wsq[idx];
                }
                if (dist < bestd || (dist == bestd && idx < bestk)) { bestd = dist; bestk = idx; }
            }
            if (lane == 0) {
                out[tbase + tok] = (float)bestk;
                bkArr[tok] = bestk;
            }
        }
    }
    __syncthreads();

    // ---- z_q: stage selected rows into LDS (coalesced row reads) ----
    {
        #pragma unroll
        for (int rr = 0; rr < 8; ++rr) {
            const int r = wv * 8 + rr;
            const int bk = bkArr[r];                              // wave-uniform
            const float4 vv = *(const float4*)(cb + (size_t)bk * DDIM + lane * 4);
            *(float4*)(lds + r * ZQ_PITCH + lane * 16) = vv;
        }
    }
    __syncthreads();

    // ---- z_q write (coalesced over tokens, sourced from LDS) ----
    {
        const int tk = tid & 63, s = tid >> 6;
        float* zq = out + TTOK + (size_t)n * (DDIM * HWSZ) + hw0 + tk;
        #pragma unroll
        for (int i = 0; i < 32; i += 4) {
            const f32x4 v = *(const f32x4*)(lds + tk * ZQ_PITCH + (s * 32 + i) * 4);
            #pragma unroll
            for (int j = 0; j < 4; ++j)
                zq[(size_t)(s * 32 + i + j) * HWSZ] = v[j];
        }
    }
}

// --------------------------------------------------------------- launch ----
extern "C" void kernel_launch(void* const* d_in, const int* in_sizes, int n_in,
                              void* d_out, int out_size, void* d_ws, size_t ws_size,
                              hipStream_t stream) {
    const float* z_e = (const float*)d_in[0];
    const float* cb  = (const float*)d_in[1];
    float* out = (float*)d_out;
    float* wsq = (float*)d_ws;                              // 2 KiB
    unsigned char* wsw = (unsigned char*)d_ws + 2048;       // 512 KiB fragment-packed w

    vq_wsq_np<<<32, 256, 0, stream>>>(cb, wsq);
    vq_wpack<<<64, 256, 0, stream>>>(cb, wsw);
    vq_main<<<NBLK, 512, 0, stream>>>(z_e, cb, wsq, wsw, out);
}